// Round 3
// baseline (153.654 us; speedup 1.0000x reference)
//
#include <hip/hip_runtime.h>

// CurvatureLoss3D — 2.5D LDS-tiled, register z-sliding fused stencil +
// curvature penalty + zero-crossing masked mean.
//
// phi: float32 [2, 1, 192, 192, 192]; out: float32 [1].
// Block: 256 threads, 32x32 xy output tile, CZ=6 z-planes (NTZ=32 -> grid
// 2304 = 9 blocks/CU exactly). Two LDS plane slots double-buffer the newest
// z-slice only; each thread keeps its 3(z)x3(y)x6(x) window in registers and
// re-reads just the new slice (3 rows x (float4+float2)) per plane. Per-slice
// row-collapsed min/max also slide in registers. Fully unrolled 6-phase
// z-loop avoids rotation movs. Per-block partial sums (no atomics/memset) if
// ws is big enough, else atomic fallback.

constexpr int DIM  = 192;
constexpr int ODIM = 190;
constexpr int TX = 32, TY = 32, CZ = 6;
constexpr int NTX = 6, NTY = 6, NTZ = 32;   // 32*6 = 192 >= 190 (z padded)
constexpr int HX = 34, HY = 34;
constexpr int LX = 36;                      // padded LDS row stride
constexpr int NBLOCKS = 2 * NTZ * NTY * NTX;  // 2304

struct Slice {
    float v[3][6];          // rows y..y+2, cols x0..x0+5 of one z-plane
    float mn[6], mx[6];     // per-column min/max over the 3 rows
};

__global__ __launch_bounds__(256, 4) void curv_main(const float* __restrict__ phi,
                                                    double* __restrict__ acc,
                                                    int use_partials) {
    __shared__ __align__(16) float tile[2][HY][LX];

    int bx = blockIdx.x;
    const int tx = bx % NTX; bx /= NTX;
    const int ty = bx % NTY; bx /= NTY;
    const int tz = bx % NTZ; bx /= NTZ;
    const int n  = bx;

    const int xbase = tx * TX, ybase = ty * TY, zbase = tz * CZ;
    const int tid = threadIdx.x;
    const float* pn = phi + (long long)n * DIM * DIM * DIM;

    auto stage = [&](int g, int slot) {
        int gz = zbase + g; if (gz > DIM - 1) gz = DIM - 1;
        const float* src = pn + gz * DIM * DIM;
#pragma unroll
        for (int it = 0; it < 5; ++it) {
            int idx = tid + it * 256;
            if (idx < HY * HX) {
                int ly = idx / HX;
                int lx = idx - ly * HX;
                int iy = ybase + ly; if (iy > DIM - 1) iy = DIM - 1;
                int ix = xbase + lx; if (ix > DIM - 1) ix = DIM - 1;
                tile[slot][ly][lx] = src[iy * DIM + ix];
            }
        }
    };

    const int row = tid >> 3;          // output y within tile (0..31)
    const int x0  = (tid & 7) * 4;     // output x within tile (0..28), 4 voxels

    auto read_slice = [&](int slot, Slice& s) {
#pragma unroll
        for (int dy = 0; dy < 3; ++dy) {
            const float* rp = &tile[slot][row + dy][x0];
            const float4 a = *(const float4*)rp;
            const float2 b = *(const float2*)(rp + 4);
            s.v[dy][0] = a.x; s.v[dy][1] = a.y; s.v[dy][2] = a.z;
            s.v[dy][3] = a.w; s.v[dy][4] = b.x; s.v[dy][5] = b.y;
        }
#pragma unroll
        for (int c = 0; c < 6; ++c) {
            s.mn[c] = fminf(fminf(s.v[0][c], s.v[1][c]), s.v[2][c]);
            s.mx[c] = fmaxf(fmaxf(s.v[0][c], s.v[1][c]), s.v[2][c]);
        }
    };

    double sp = 0.0, sc = 0.0;
    const float EPSF = 1e-8f;
    const int oy = ybase + row;
    const bool vy = (oy < ODIM);

    // s0 = plane zo, s1 = plane zo+1, s2 = plane zo+2
    auto compute = [&](const Slice& s0, const Slice& s1, const Slice& s2, int zo) {
        const int oz = zbase + zo;
        const bool vzy = vy && (oz < ODIM);

        float colmn[6], colmx[6];
#pragma unroll
        for (int c = 0; c < 6; ++c) {
            colmn[c] = fminf(fminf(s0.mn[c], s1.mn[c]), s2.mn[c]);
            colmx[c] = fmaxf(fmaxf(s0.mx[c], s1.mx[c]), s2.mx[c]);
        }

#pragma unroll
        for (int j = 0; j < 4; ++j) {
            const int ox = xbase + x0 + j;
            const bool valid = vzy && (ox < ODIM);

            float gx = 0.5f * (s2.v[1][j + 1] - s0.v[1][j + 1]);
            float gy = 0.5f * (s1.v[2][j + 1] - s1.v[0][j + 1]);
            float gz = 0.5f * (s1.v[1][j + 2] - s1.v[1][j]);

            float c2  = 2.0f * s1.v[1][j + 1];
            float hxx = s0.v[1][j + 1] - c2 + s2.v[1][j + 1];
            float hyy = s1.v[0][j + 1] - c2 + s1.v[2][j + 1];
            float hzz = s1.v[1][j] - c2 + s1.v[1][j + 2];

            float hxy = 0.25f * (s0.v[0][j + 1] - s0.v[2][j + 1]
                               - s2.v[0][j + 1] + s2.v[2][j + 1]);
            float hxz = 0.25f * (s0.v[1][j] - s0.v[1][j + 2]
                               - s2.v[1][j] + s2.v[1][j + 2]);
            float hyz = 0.25f * (s1.v[0][j] - s1.v[0][j + 2]
                               - s1.v[2][j] + s1.v[2][j + 2]);

            float gx2 = gx * gx, gy2 = gy * gy, gz2 = gz * gz;
            float mag  = sqrtf(gx2 + gy2 + gz2 + EPSF);
            float mag3 = mag * mag * mag;

            float cross = gx * gy * hxy + gx * gz * hxz + gy * gz * hyz;
            float inv_mag3 = __builtin_amdgcn_rcpf(mag3 + EPSF);
            float inv_mag  = __builtin_amdgcn_rcpf(mag  + EPSF);

            float mean_c = (gx2 * (hyy + hzz) + gy2 * (hxx + hzz) +
                            gz2 * (hxx + hyy) - 2.0f * cross) * inv_mag3;
            float lap   = (hxx + hyy + hzz) * inv_mag;
            float quad  = (gx2 * hxx + gy2 * hyy + gz2 * hzz + 2.0f * cross) * inv_mag3;
            float gauss = lap - quad;

            float k1  = mean_c + sqrtf(fabsf(mean_c * mean_c - gauss) + EPSF);
            float t   = k1 * 2.0f;           // k1 / (0.5 + 1e-8) == k1 * 2 in f32
            float pen = fmaxf(t * t - 1.0f, 0.0f);

            float mn = fminf(fminf(colmn[j], colmn[j + 1]), colmn[j + 2]);
            float mx = fmaxf(fmaxf(colmx[j], colmx[j + 1]), colmx[j + 2]);

            if (valid && (mn * mx < 0.0f)) {
                sp += (double)pen;
                sc += 1.0;
            }
        }
    };

    Slice s0, s1, s2;
    stage(0, 0);
    stage(1, 1);
    __syncthreads();
    read_slice(0, s0);
    read_slice(1, s1);
    __syncthreads();                    // protect slot0 before zo=0 overwrite

    // 6-phase unrolled z-loop: stage plane zo+2 -> slot zo&1; sync; read; compute.
    stage(2, 0); __syncthreads(); read_slice(0, s2); compute(s0, s1, s2, 0);
    stage(3, 1); __syncthreads(); read_slice(1, s0); compute(s1, s2, s0, 1);
    stage(4, 0); __syncthreads(); read_slice(0, s1); compute(s2, s0, s1, 2);
    stage(5, 1); __syncthreads(); read_slice(1, s2); compute(s0, s1, s2, 3);
    stage(6, 0); __syncthreads(); read_slice(0, s0); compute(s1, s2, s0, 4);
    stage(7, 1); __syncthreads(); read_slice(1, s1); compute(s2, s0, s1, 5);

    // wave-64 reduction
#pragma unroll
    for (int off = 32; off > 0; off >>= 1) {
        sp += __shfl_down(sp, off, 64);
        sc += __shfl_down(sc, off, 64);
    }

    __shared__ double lsp[4], lsc[4];
    const int wave = tid >> 6, lane = tid & 63;
    if (lane == 0) { lsp[wave] = sp; lsc[wave] = sc; }
    __syncthreads();
    if (tid == 0) {
        double tp = lsp[0] + lsp[1] + lsp[2] + lsp[3];
        double tc = lsc[0] + lsc[1] + lsc[2] + lsc[3];
        if (use_partials) {
            acc[2 * blockIdx.x]     = tp;
            acc[2 * blockIdx.x + 1] = tc;
        } else {
            atomicAdd(&acc[0], tp);
            atomicAdd(&acc[1], tc);
        }
    }
}

__global__ __launch_bounds__(256) void curv_reduce(const double* __restrict__ part,
                                                   int nblocks, int use_partials,
                                                   float* __restrict__ out) {
    double sp = 0.0, sc = 0.0;
    if (use_partials) {
        for (int i = threadIdx.x; i < nblocks; i += 256) {
            sp += part[2 * i];
            sc += part[2 * i + 1];
        }
    } else if (threadIdx.x == 0) {
        sp = part[0]; sc = part[1];
    }
#pragma unroll
    for (int off = 32; off > 0; off >>= 1) {
        sp += __shfl_down(sp, off, 64);
        sc += __shfl_down(sc, off, 64);
    }
    __shared__ double lsp[4], lsc[4];
    const int wave = threadIdx.x >> 6, lane = threadIdx.x & 63;
    if (lane == 0) { lsp[wave] = sp; lsc[wave] = sc; }
    __syncthreads();
    if (threadIdx.x == 0) {
        double tp = lsp[0] + lsp[1] + lsp[2] + lsp[3];
        double tc = lsc[0] + lsc[1] + lsc[2] + lsc[3];
        out[0] = (float)(tp / (tc + 1e-8));
    }
}

extern "C" void kernel_launch(void* const* d_in, const int* in_sizes, int n_in,
                              void* d_out, int out_size, void* d_ws, size_t ws_size,
                              hipStream_t stream) {
    const float* phi = (const float*)d_in[0];
    float* out = (float*)d_out;
    double* acc = (double*)d_ws;

    const int use_partials = (ws_size >= (size_t)(2 * NBLOCKS) * sizeof(double)) ? 1 : 0;
    if (!use_partials) {
        hipMemsetAsync(d_ws, 0, 2 * sizeof(double), stream);
    }

    curv_main<<<NBLOCKS, 256, 0, stream>>>(phi, acc, use_partials);
    curv_reduce<<<1, 256, 0, stream>>>(acc, NBLOCKS, use_partials, out);
}

// Round 4
// 118.692 us; speedup vs baseline: 1.2946x; 1.2946x over previous
//
#include <hip/hip_runtime.h>

// CurvatureLoss3D — 2.5D LDS-tiled, register z-sliding, software-pipelined
// staging (pref plane k+3 to VGPRs while computing plane k; commit to LDS one
// phase later so global-load latency is hidden behind compute).
//
// phi: float32 [2, 1, 192, 192, 192]; out: float32 [1].
// Block: 256 threads, 32x32 xy tile, CZ=6 z-planes (grid 2304 = 9 blocks/CU).
// 3 rotating LDS plane slots, one barrier per phase. Staging index is clamped
// (not predicated): duplicate lanes re-load/re-write the same value.

constexpr int DIM  = 192;
constexpr int ODIM = 190;
constexpr int TX = 32, TY = 32, CZ = 6;
constexpr int NTX = 6, NTY = 6, NTZ = 32;   // 32*6 = 192 >= 190
constexpr int HX = 34, HY = 34;
constexpr int LX = 36;                      // padded LDS row stride (16B rows)
constexpr int NELEM = HX * HY;              // 1156 staged elements per plane
constexpr int NBLOCKS = 2 * NTZ * NTY * NTX;  // 2304

struct Slice {
    float v[3][6];          // rows y..y+2, cols x0..x0+5 of one z-plane
    float mn[6], mx[6];     // per-column min/max over the 3 rows
};

__global__ __launch_bounds__(256, 4) void curv_main(const float* __restrict__ phi,
                                                    double* __restrict__ acc,
                                                    int use_partials) {
    __shared__ __align__(16) float tile[3][HY][LX];

    int bx = blockIdx.x;
    const int tx = bx % NTX; bx /= NTX;
    const int ty = bx % NTY; bx /= NTY;
    const int tz = bx % NTZ; bx /= NTZ;
    const int n  = bx;

    const int xbase = tx * TX, ybase = ty * TY, zbase = tz * CZ;
    const int tid = threadIdx.x;
    const float* pn = phi + (long long)n * DIM * DIM * DIM;

    // ---- staging maps, hoisted out of the z-loop ----
    int goff[5], loff[5];
#pragma unroll
    for (int it = 0; it < 5; ++it) {
        int idx = tid + it * 256; if (idx > NELEM - 1) idx = NELEM - 1;
        int ly = idx / HX, lx = idx - ly * HX;
        int iy = ybase + ly; if (iy > DIM - 1) iy = DIM - 1;
        int ix = xbase + lx; if (ix > DIM - 1) ix = DIM - 1;
        goff[it] = iy * DIM + ix;
        loff[it] = ly * LX + lx;
    }

    float pf[5];
    auto pref = [&](int g) {                 // global -> VGPR, no wait
        int gz = zbase + g; if (gz > DIM - 1) gz = DIM - 1;
        const float* src = pn + gz * DIM * DIM;
#pragma unroll
        for (int it = 0; it < 5; ++it) pf[it] = src[goff[it]];
    };
    float* tf = &tile[0][0][0];
    auto commit = [&](int slot) {            // VGPR -> LDS (waits the pref)
        float* t = tf + slot * (HY * LX);
#pragma unroll
        for (int it = 0; it < 5; ++it) t[loff[it]] = pf[it];
    };

    const int row = tid >> 3;          // output y within tile (0..31)
    const int x0  = (tid & 7) * 4;     // output x within tile (0..28)

    auto read_slice = [&](int slot, Slice& s) {
#pragma unroll
        for (int dy = 0; dy < 3; ++dy) {
            const float* rp = &tile[slot][row + dy][x0];
            const float4 a = *(const float4*)rp;
            const float2 b = *(const float2*)(rp + 4);
            s.v[dy][0] = a.x; s.v[dy][1] = a.y; s.v[dy][2] = a.z;
            s.v[dy][3] = a.w; s.v[dy][4] = b.x; s.v[dy][5] = b.y;
        }
#pragma unroll
        for (int c = 0; c < 6; ++c) {
            s.mn[c] = fminf(fminf(s.v[0][c], s.v[1][c]), s.v[2][c]);
            s.mx[c] = fmaxf(fmaxf(s.v[0][c], s.v[1][c]), s.v[2][c]);
        }
    };

    double sp = 0.0, sc = 0.0;
    const float EPSF = 1e-8f;
    const int oy = ybase + row;
    const bool vy = (oy < ODIM);

    auto compute = [&](const Slice& s0, const Slice& s1, const Slice& s2, int zo) {
        const int oz = zbase + zo;
        if (oz >= ODIM) return;              // block-uniform skip

        float colmn[6], colmx[6];
#pragma unroll
        for (int c = 0; c < 6; ++c) {
            colmn[c] = fminf(fminf(s0.mn[c], s1.mn[c]), s2.mn[c]);
            colmx[c] = fmaxf(fmaxf(s0.mx[c], s1.mx[c]), s2.mx[c]);
        }

        float fsp = 0.0f, fsc = 0.0f;
#pragma unroll
        for (int j = 0; j < 4; ++j) {
            const int ox = xbase + x0 + j;
            const bool valid = vy && (ox < ODIM);

            float gx = 0.5f * (s2.v[1][j + 1] - s0.v[1][j + 1]);
            float gy = 0.5f * (s1.v[2][j + 1] - s1.v[0][j + 1]);
            float gz = 0.5f * (s1.v[1][j + 2] - s1.v[1][j]);

            float c2  = 2.0f * s1.v[1][j + 1];
            float hxx = s0.v[1][j + 1] - c2 + s2.v[1][j + 1];
            float hyy = s1.v[0][j + 1] - c2 + s1.v[2][j + 1];
            float hzz = s1.v[1][j] - c2 + s1.v[1][j + 2];

            float hxy = 0.25f * (s0.v[0][j + 1] - s0.v[2][j + 1]
                               - s2.v[0][j + 1] + s2.v[2][j + 1]);
            float hxz = 0.25f * (s0.v[1][j] - s0.v[1][j + 2]
                               - s2.v[1][j] + s2.v[1][j + 2]);
            float hyz = 0.25f * (s1.v[0][j] - s1.v[0][j + 2]
                               - s1.v[2][j] + s1.v[2][j + 2]);

            float gx2 = gx * gx, gy2 = gy * gy, gz2 = gz * gz;
            float mag  = sqrtf(gx2 + gy2 + gz2 + EPSF);
            float mag3 = mag * mag * mag;

            float cross = gx * gy * hxy + gx * gz * hxz + gy * gz * hyz;
            float inv_mag3 = __builtin_amdgcn_rcpf(mag3 + EPSF);
            float inv_mag  = __builtin_amdgcn_rcpf(mag  + EPSF);

            float mean_c = (gx2 * (hyy + hzz) + gy2 * (hxx + hzz) +
                            gz2 * (hxx + hyy) - 2.0f * cross) * inv_mag3;
            float lap   = (hxx + hyy + hzz) * inv_mag;
            float quad  = (gx2 * hxx + gy2 * hyy + gz2 * hzz + 2.0f * cross) * inv_mag3;
            float gauss = lap - quad;

            float k1  = mean_c + sqrtf(fabsf(mean_c * mean_c - gauss) + EPSF);
            float t   = k1 * 2.0f;           // k1 / (0.5 + 1e-8) == 2*k1 in f32
            float pen = fmaxf(t * t - 1.0f, 0.0f);

            float mn = fminf(fminf(colmn[j], colmn[j + 1]), colmn[j + 2]);
            float mx = fmaxf(fmaxf(colmx[j], colmx[j + 1]), colmx[j + 2]);

            if (valid && (mn * mx < 0.0f)) {
                fsp += pen;
                fsc += 1.0f;
            }
        }
        sp += (double)fsp;
        sc += (double)fsc;
    };

    Slice s0, s1, s2;

    // ---- prologue: planes 0,1 staged; plane 2 in flight ----
    pref(0); commit(0);
    pref(1); commit(1);
    pref(2);
    __syncthreads();
    read_slice(0, s0);
    read_slice(1, s1);

    // ---- pipelined phases: commit plane zo+2, prefetch zo+3, sync, read, compute ----
    commit(2); pref(3); __syncthreads(); read_slice(2, s2); compute(s0, s1, s2, 0);
    commit(0); pref(4); __syncthreads(); read_slice(0, s0); compute(s1, s2, s0, 1);
    commit(1); pref(5); __syncthreads(); read_slice(1, s1); compute(s2, s0, s1, 2);
    commit(2); pref(6); __syncthreads(); read_slice(2, s2); compute(s0, s1, s2, 3);
    commit(0); pref(7); __syncthreads(); read_slice(0, s0); compute(s1, s2, s0, 4);
    commit(1);          __syncthreads(); read_slice(1, s1); compute(s2, s0, s1, 5);

    // ---- reduction ----
#pragma unroll
    for (int off = 32; off > 0; off >>= 1) {
        sp += __shfl_down(sp, off, 64);
        sc += __shfl_down(sc, off, 64);
    }

    __shared__ double lsp[4], lsc[4];
    const int wave = tid >> 6, lane = tid & 63;
    if (lane == 0) { lsp[wave] = sp; lsc[wave] = sc; }
    __syncthreads();
    if (tid == 0) {
        double tp = lsp[0] + lsp[1] + lsp[2] + lsp[3];
        double tc = lsc[0] + lsc[1] + lsc[2] + lsc[3];
        if (use_partials) {
            acc[2 * blockIdx.x]     = tp;
            acc[2 * blockIdx.x + 1] = tc;
        } else {
            atomicAdd(&acc[0], tp);
            atomicAdd(&acc[1], tc);
        }
    }
}

__global__ __launch_bounds__(256) void curv_reduce(const double* __restrict__ part,
                                                   int nblocks, int use_partials,
                                                   float* __restrict__ out) {
    double sp = 0.0, sc = 0.0;
    if (use_partials) {
        for (int i = threadIdx.x; i < nblocks; i += 256) {
            sp += part[2 * i];
            sc += part[2 * i + 1];
        }
    } else if (threadIdx.x == 0) {
        sp = part[0]; sc = part[1];
    }
#pragma unroll
    for (int off = 32; off > 0; off >>= 1) {
        sp += __shfl_down(sp, off, 64);
        sc += __shfl_down(sc, off, 64);
    }
    __shared__ double lsp[4], lsc[4];
    const int wave = threadIdx.x >> 6, lane = threadIdx.x & 63;
    if (lane == 0) { lsp[wave] = sp; lsc[wave] = sc; }
    __syncthreads();
    if (threadIdx.x == 0) {
        double tp = lsp[0] + lsp[1] + lsp[2] + lsp[3];
        double tc = lsc[0] + lsc[1] + lsc[2] + lsc[3];
        out[0] = (float)(tp / (tc + 1e-8));
    }
}

extern "C" void kernel_launch(void* const* d_in, const int* in_sizes, int n_in,
                              void* d_out, int out_size, void* d_ws, size_t ws_size,
                              hipStream_t stream) {
    const float* phi = (const float*)d_in[0];
    float* out = (float*)d_out;
    double* acc = (double*)d_ws;

    const int use_partials = (ws_size >= (size_t)(2 * NBLOCKS) * sizeof(double)) ? 1 : 0;
    if (!use_partials) {
        hipMemsetAsync(d_ws, 0, 2 * sizeof(double), stream);
    }

    curv_main<<<NBLOCKS, 256, 0, stream>>>(phi, acc, use_partials);
    curv_reduce<<<1, 256, 0, stream>>>(acc, NBLOCKS, use_partials, out);
}